// Round 7
// baseline (231.284 us; speedup 1.0000x reference)
//
#include <hip/hip_runtime.h>
#include <math.h>

// Problem constants
#define B  16384
#define K  1024
#define D  512
#define EPS 1e-12f

// softmax in base-2: log2(e^{(s+g)/tau}) = SM_C1*s - 10*log2(-log2(u)) + SM_C2
//   tau = 0.1 ; SM_C1 = 10*log2(e) ; SM_C2 = -10*log2(ln 2)
#define SM_C1 14.426950408889634f
#define SM_C2 5.287663729448977f

typedef unsigned short ushort_t;

// raw gfx950 transcendentals: v_log_f32 = log2(x), v_exp_f32 = 2^x
#define LOG2F(x) __builtin_amdgcn_logf(x)
#define EXP2F(x) __builtin_amdgcn_exp2f(x)

// d_out layout (floats): [0, B*D) pt ; [B*D, B*D+K*D) p ; then sim_loss, div_loss
#define OUT_PT   0
#define OUT_P    (B*D)
#define OUT_SIM  (B*D + K*D)
#define OUT_DIV  (B*D + K*D + 1)

// ws layout (floats):
//  [1024,2048)      softmax per-block dot partials (1024)
//  [32768, +B*K/2)  simh f16 [B][1024]; after softmax same bytes hold Eh f16
//  then Ph   [1024][512] f16 (1 MB)
//  then PTh  [512][1024] f16 (1 MB)
//  then DIAGP[256], COLP[256][512]  (norm_p per-block partials, no atomics)
#define WS_RED   1024
#define WS_SIM   32768
#define WS_PH    (WS_SIM + (B*K)/2)
#define WS_PTH   (WS_PH + (K*D)/2)
#define WS_DIAGP (WS_PTH + (K*D)/2)
#define WS_COLP  (WS_DIAGP + 256)

// Xh f16 [16384][512] (16 MB) lives in d_out's pt region, consumed by gemm1
// before gemm2 overwrites pt.

typedef _Float16 half8 __attribute__((ext_vector_type(8)));
typedef float f32x4 __attribute__((ext_vector_type(4)));

__device__ __forceinline__ float wave_reduce_sum(float v) {
    #pragma unroll
    for (int off = 32; off >= 1; off >>= 1) v += __shfl_down(v, off);
    return v;
}
__device__ __forceinline__ float wave_reduce_max(float v) {
    #pragma unroll
    for (int off = 32; off >= 1; off >>= 1) v = fmaxf(v, __shfl_down(v, off));
    return v;
}

__device__ __forceinline__ ushort_t f2h(float f) {
    _Float16 h = (_Float16)f;
    return __builtin_bit_cast(ushort_t, h);
}
__device__ __forceinline__ float h2f(ushort_t u) {
    return (float)__builtin_bit_cast(_Float16, u);
}

__device__ __forceinline__ void async16(const void* g, void* l) {
    __builtin_amdgcn_global_load_lds(
        (const __attribute__((address_space(1))) unsigned int*)g,
        (__attribute__((address_space(3))) unsigned int*)l, 16, 0, 0);
}

// Normalize prototypes (one wave per row, 4 rows/block). Fused outputs:
//  - phat fp32 -> d_out (output 1)
//  - Ph f16 [1024][512]
//  - per-block colsum partial [512] -> ws[WS_COLP + blk*512]
//  - per-block diag partial -> ws[WS_DIAGP + blk]
__global__ __launch_bounds__(256) void norm_p_kernel(const float* __restrict__ proto,
                                                     float* __restrict__ out,
                                                     float* __restrict__ ws,
                                                     ushort_t* __restrict__ Ph) {
    __shared__ float cs[4][512];
    __shared__ float red[4];
    int tid = threadIdx.x, wid = tid >> 6, lane = tid & 63;
    int row = blockIdx.x * 4 + wid;
    const float4* pr = (const float4*)(proto + (size_t)row * D);
    float4 a = pr[lane * 2], b = pr[lane * 2 + 1];
    float ss = a.x*a.x + a.y*a.y + a.z*a.z + a.w*a.w
             + b.x*b.x + b.y*b.y + b.z*b.z + b.w*b.w;
    ss = wave_reduce_sum(ss);
    ss = __shfl(ss, 0);
    float inv = 1.0f / fmaxf(sqrtf(ss), EPS);
    float4 na = make_float4(a.x*inv, a.y*inv, a.z*inv, a.w*inv);
    float4 nb = make_float4(b.x*inv, b.y*inv, b.z*inv, b.w*inv);
    float4* po = (float4*)(out + OUT_P + (size_t)row * D);
    po[lane * 2]     = na;
    po[lane * 2 + 1] = nb;
    ushort4* ph = (ushort4*)(Ph + (size_t)row * D);
    ph[lane * 2]     = make_ushort4(f2h(na.x), f2h(na.y), f2h(na.z), f2h(na.w));
    ph[lane * 2 + 1] = make_ushort4(f2h(nb.x), f2h(nb.y), f2h(nb.z), f2h(nb.w));
    *(float4*)(&cs[wid][lane * 8])     = na;
    *(float4*)(&cs[wid][lane * 8 + 4]) = nb;
    if (lane == 0) red[wid] = ss * inv * inv;
    __syncthreads();
    float c0 = cs[0][tid] + cs[1][tid] + cs[2][tid] + cs[3][tid];
    float c1 = cs[0][tid + 256] + cs[1][tid + 256] + cs[2][tid + 256] + cs[3][tid + 256];
    ws[WS_COLP + (size_t)blockIdx.x * 512 + tid]       = c0;
    ws[WS_COLP + (size_t)blockIdx.x * 512 + tid + 256] = c1;
    if (tid == 0) ws[WS_DIAGP + blockIdx.x] = red[0] + red[1] + red[2] + red[3];
}

// PTh [512][1024] f16: transpose of phat
__global__ __launch_bounds__(256) void ptcvt_kernel(const float* __restrict__ out,
                                                    ushort_t* __restrict__ PT) {
    __shared__ float tile[64][65];
    int k0 = blockIdx.x * 64, d0 = blockIdx.y * 64;
    int tid = threadIdx.x;
    const float* phat = out + OUT_P;
    #pragma unroll
    for (int i = tid; i < 64 * 64; i += 256) {
        int kk = i >> 6, dd = i & 63;
        tile[dd][kk] = phat[(size_t)(k0 + kk) * D + d0 + dd];
    }
    __syncthreads();
    #pragma unroll
    for (int i = tid; i < 64 * 64; i += 256) {
        int dd = i >> 6, kk = i & 63;
        PT[(size_t)(d0 + dd) * K + k0 + kk] = f2h(tile[dd][kk]);
    }
}

// Fused x row-norm + f16 convert: Xh [16384][512] in out's pt region.
__global__ __launch_bounds__(256) void xcvt_kernel(const float* __restrict__ x,
                                                   ushort_t* __restrict__ Xh) {
    int wid = threadIdx.x >> 6, lane = threadIdx.x & 63;
    int row = blockIdx.x * 4 + wid;
    const float4* xr = (const float4*)(x + (size_t)row * D);
    float4 a = xr[lane * 2], b = xr[lane * 2 + 1];
    float ss = a.x*a.x + a.y*a.y + a.z*a.z + a.w*a.w
             + b.x*b.x + b.y*b.y + b.z*b.z + b.w*b.w;
    ss = wave_reduce_sum(ss);
    ss = __shfl(ss, 0);
    float inv = 1.0f / fmaxf(sqrtf(ss), EPS);
    ushort4 h0 = make_ushort4(f2h(a.x*inv), f2h(a.y*inv), f2h(a.z*inv), f2h(a.w*inv));
    ushort4 h1 = make_ushort4(f2h(b.x*inv), f2h(b.y*inv), f2h(b.z*inv), f2h(b.w*inv));
    ushort4* xo = (ushort4*)(Xh + (size_t)row * D);
    xo[lane * 2]     = h0;
    xo[lane * 2 + 1] = h1;
}

// ---------------------------------------------------------------------------
// 256-row 8-wave pipelined bt-GEMM (T3+T4: 4 phases/K-tile, counted vmcnt).
// BM=256, BN template (256 for gemm1, 128 for gemm2), BK=64, 512 threads,
// waves 2M x 4N, per-wave 128 x BN/4 output. LDS: A[2][256][64] + B[2][BN][64]
// f16, XOR-16B swizzle (linear DMA dest + inverse-swizzled global source +
// swizzled ds_read -> ~2-way banks). Stage of tile t+1 is issued spread over
// tile t's 4 phases in dependency order (A-even, B, A-odd); waits are COUNTED:
// vmcnt(2) at tile boundary (A-odd halves may stay in flight), vmcnt(4) before
// phase 2 (A-odd needed). Raw s_barrier (no __syncthreads drain) per phase.
// ---------------------------------------------------------------------------
template<int BN, int LDA, int LDB, int LDC, int KK, bool F16C>
__global__ __launch_bounds__(512, 2) void gemm256(const ushort_t* __restrict__ A,
                                                  const ushort_t* __restrict__ Bm,
                                                  void* __restrict__ Cv) {
    constexpr int TJ  = BN / 64;   // 16x16 col-tiles per wave: 4 or 2
    constexpr int TJH = TJ / 2;    // col-tiles per phase: 2 or 1
    constexpr int BCH = BN / 64;   // B stage chunks per thread per tile: 4 or 2
    constexpr int NT  = KK / 64;
    __shared__ __align__(16) ushort_t As[2][256 * 64];
    __shared__ __align__(16) ushort_t Bs[2][BN * 64];

    int tid = threadIdx.x;
    int wid = tid >> 6, lane = tid & 63;
    int quad = lane >> 4, l16 = lane & 15;
    int wm = (wid & 1) * 128;
    int wn = (wid >> 1) * (BN / 4);
    int bn0 = blockIdx.x * BN, bm0 = blockIdx.y * 256;

    f32x4 acc[8][TJ] = {};

    // stage helpers: chunk c = q*512 + tid; LDS linear byte 16*c;
    // logical (row = c>>3, sub16B = c&7); global sub' = sub ^ (row&7)
    auto stageA = [&](int buf, int kc, int q) {
        int c = q * 512 + tid;
        int row = c >> 3, sub = c & 7;
        async16(A + (size_t)(bm0 + row) * LDA + kc + ((sub ^ (row & 7)) << 3),
                &As[buf][(size_t)(q * 512 + wid * 64) * 8]);
    };
    auto stageB = [&](int buf, int kc, int q) {
        int c = q * 512 + tid;
        int row = c >> 3, sub = c & 7;
        async16(Bm + (size_t)(bn0 + row) * LDB + kc + ((sub ^ (row & 7)) << 3),
                &Bs[buf][(size_t)(q * 512 + wid * 64) * 8]);
    };
    // fragment read: tile row r, 16B chunk x (= ks*4+quad), swizzled
    auto rdA = [&](int buf, int r, int x) -> half8 {
        return *(const half8*)(&As[buf][(size_t)r * 64 + ((x ^ (r & 7)) << 3)]);
    };
    auto rdB = [&](int buf, int r, int x) -> half8 {
        return *(const half8*)(&Bs[buf][(size_t)r * 64 + ((x ^ (r & 7)) << 3)]);
    };

    // prologue: stage tile 0 fully, drain, barrier
    #pragma unroll
    for (int q = 0; q < 4; ++q) stageA(0, 0, q);
    #pragma unroll
    for (int q = 0; q < BCH; ++q) stageB(0, 0, q);
    asm volatile("s_waitcnt vmcnt(0)" ::: "memory");
    __builtin_amdgcn_s_barrier();

    int cur = 0;
    for (int t = 0; t < NT; ++t) {
        int kc2 = (t + 1) * 64;
        bool pf = (t + 1 < NT);
        #pragma unroll
        for (int p = 0; p < 4; ++p) {
            // phase-2 entry: A-odd halves of THIS tile must have landed.
            if (p == 2) {
                if (pf) asm volatile("s_waitcnt vmcnt(4)" ::: "memory");
                else    asm volatile("s_waitcnt vmcnt(0)" ::: "memory");
            }
            // issue next-tile stage quarter (dependency order: A-even, B, A-odd)
            if (pf) {
                if (BN == 256) {
                    if      (p == 0) { stageA(cur ^ 1, kc2, 0); stageA(cur ^ 1, kc2, 2); }
                    else if (p == 1) { stageB(cur ^ 1, kc2, 0); stageB(cur ^ 1, kc2, 1); }
                    else if (p == 2) { stageB(cur ^ 1, kc2, 2); stageB(cur ^ 1, kc2, 3); }
                    else             { stageA(cur ^ 1, kc2, 1); stageA(cur ^ 1, kc2, 3); }
                } else {
                    if      (p == 0) { stageA(cur ^ 1, kc2, 0); stageA(cur ^ 1, kc2, 2); }
                    else if (p == 1) { stageB(cur ^ 1, kc2, 0); stageB(cur ^ 1, kc2, 1); }
                    else if (p == 2) { stageA(cur ^ 1, kc2, 1); }
                    else             { stageA(cur ^ 1, kc2, 3); }
                }
            }
            const int ih = p >> 1, jh = p & 1;
            half8 af[4][2], bf[TJH][2];
            #pragma unroll
            for (int ii = 0; ii < 4; ++ii)
                #pragma unroll
                for (int ks = 0; ks < 2; ++ks)
                    af[ii][ks] = rdA(cur, wm + (ih * 4 + ii) * 16 + l16, ks * 4 + quad);
            #pragma unroll
            for (int jj = 0; jj < TJH; ++jj)
                #pragma unroll
                for (int ks = 0; ks < 2; ++ks)
                    bf[jj][ks] = rdB(cur, wn + (jh * TJH + jj) * 16 + l16, ks * 4 + quad);
            __builtin_amdgcn_s_setprio(1);
            #pragma unroll
            for (int ii = 0; ii < 4; ++ii)
                #pragma unroll
                for (int jj = 0; jj < TJH; ++jj) {
                    acc[ih*4+ii][jh*TJH+jj] = __builtin_amdgcn_mfma_f32_16x16x32_f16(
                        af[ii][0], bf[jj][0], acc[ih*4+ii][jh*TJH+jj], 0, 0, 0);
                    acc[ih*4+ii][jh*TJH+jj] = __builtin_amdgcn_mfma_f32_16x16x32_f16(
                        af[ii][1], bf[jj][1], acc[ih*4+ii][jh*TJH+jj], 0, 0, 0);
                }
            __builtin_amdgcn_s_setprio(0);
            if (p < 3) __builtin_amdgcn_s_barrier();
        }
        // tile boundary: next tile's stage must be usable except A-odd halves
        if (pf) asm volatile("s_waitcnt vmcnt(2)" ::: "memory");
        else    asm volatile("s_waitcnt vmcnt(0)" ::: "memory");
        __builtin_amdgcn_s_barrier();
        cur ^= 1;
    }

    #pragma unroll
    for (int i = 0; i < 8; ++i)
        #pragma unroll
        for (int j = 0; j < TJ; ++j)
            #pragma unroll
            for (int r = 0; r < 4; ++r) {
                int row = bm0 + wm + 16 * i + quad * 4 + r;
                int col = bn0 + wn + 16 * j + l16;
                if (F16C)
                    ((ushort_t*)Cv)[(size_t)row * LDC + col] = f2h(acc[i][j][r]);
                else
                    ((float*)Cv)[(size_t)row * LDC + col] = acc[i][j][r];
            }
}

// Row softmax with gumbel, base-2 domain (2x v_log + 1x v_exp per element).
// One WAVE per row, 4 rows/wave. Reads simh f16, writes Eh f16 in-place.
__global__ __launch_bounds__(256) void softmax_rows(const float* __restrict__ u,
                                                    float* __restrict__ ws) {
    ushort_t* simh = (ushort_t*)(ws + WS_SIM);
    int tid = threadIdx.x;
    int wid = tid >> 6, lane = tid & 63;
    int gw = blockIdx.x * 4 + wid;        // 0..4095
    float dotacc = 0.0f;

    for (int r = 0; r < 4; ++r) {
        int row = gw + 4096 * r;
        ushort4* srow = (ushort4*)(simh + (size_t)row * K);
        const float4* urow = (const float4*)(u + (size_t)row * K);
        float4 s[4], z[4];
        #pragma unroll
        for (int j = 0; j < 4; ++j) {
            ushort4 sh = srow[lane + 64 * j];
            float4 uu = urow[lane + 64 * j];
            s[j] = make_float4(h2f(sh.x), h2f(sh.y), h2f(sh.z), h2f(sh.w));
            z[j].x = SM_C1 * s[j].x - 10.0f * LOG2F(-LOG2F(uu.x)) + SM_C2;
            z[j].y = SM_C1 * s[j].y - 10.0f * LOG2F(-LOG2F(uu.y)) + SM_C2;
            z[j].z = SM_C1 * s[j].z - 10.0f * LOG2F(-LOG2F(uu.z)) + SM_C2;
            z[j].w = SM_C1 * s[j].w - 10.0f * LOG2F(-LOG2F(uu.w)) + SM_C2;
        }
        float m = z[0].x;
        #pragma unroll
        for (int j = 0; j < 4; ++j)
            m = fmaxf(m, fmaxf(fmaxf(z[j].x, z[j].y), fmaxf(z[j].z, z[j].w)));
        m = wave_reduce_max(m);
        m = __shfl(m, 0);

        float4 e[4];
        float l = 0.0f;
        #pragma unroll
        for (int j = 0; j < 4; ++j) {
            e[j].x = EXP2F(z[j].x - m);
            e[j].y = EXP2F(z[j].y - m);
            e[j].z = EXP2F(z[j].z - m);
            e[j].w = EXP2F(z[j].w - m);
            l += e[j].x + e[j].y + e[j].z + e[j].w;
        }
        l = wave_reduce_sum(l);
        l = __shfl(l, 0);
        float inv = 1.0f / l;

        #pragma unroll
        for (int j = 0; j < 4; ++j) {
            float ex = e[j].x * inv, ey = e[j].y * inv,
                  ez = e[j].z * inv, ew = e[j].w * inv;
            srow[lane + 64 * j] = make_ushort4(f2h(ex), f2h(ey), f2h(ez), f2h(ew));
            dotacc += ex * s[j].x + ey * s[j].y + ez * s[j].z + ew * s[j].w;
        }
    }

    dotacc = wave_reduce_sum(dotacc);
    __shared__ float red[4];
    if (lane == 0) red[wid] = dotacc;
    __syncthreads();
    if (tid == 0) ws[WS_RED + blockIdx.x] = red[0] + red[1] + red[2] + red[3];
}

// Final reduction, 1024 threads: softmax dot partials (1024), diag partials
// (256), colsum partials (256 x 512 -> ||colsum||^2).
__global__ __launch_bounds__(1024) void finalize_kernel(float* __restrict__ out,
                                                        const float* __restrict__ ws) {
    __shared__ float cred[1024];
    __shared__ float rd[16], rs[16], rg[16];
    int tid = threadIdx.x, wid = tid >> 6, lane = tid & 63;
    int col = tid & 511, h = tid >> 9;    // h=0: b2 0..127, h=1: b2 128..255
    float c = 0.0f;
    #pragma unroll 8
    for (int b2 = h * 128; b2 < h * 128 + 128; ++b2)
        c += ws[WS_COLP + (size_t)b2 * 512 + col];
    cred[tid] = c;
    float vdot = ws[WS_RED + tid];
    float diag = (tid < 256) ? ws[WS_DIAGP + tid] : 0.0f;
    __syncthreads();
    float vssq = 0.0f;
    if (tid < 512) {
        float cc = cred[tid] + cred[tid + 512];
        vssq = cc * cc;
    }
    vdot = wave_reduce_sum(vdot);
    vssq = wave_reduce_sum(vssq);
    diag = wave_reduce_sum(diag);
    if (lane == 0) { rd[wid] = vdot; rs[wid] = vssq; rg[wid] = diag; }
    __syncthreads();
    if (tid == 0) {
        float dot = 0.0f, ssq = 0.0f, dg = 0.0f;
        #pragma unroll
        for (int w = 0; w < 16; ++w) { dot += rd[w]; ssq += rs[w]; dg += rg[w]; }
        out[OUT_SIM] = 1.0f - dot * (1.0f / (float)B);
        out[OUT_DIV] = ssq - dg;
    }
}

extern "C" void kernel_launch(void* const* d_in, const int* in_sizes, int n_in,
                              void* d_out, int out_size, void* d_ws, size_t ws_size,
                              hipStream_t stream) {
    const float* input  = (const float*)d_in[0];
    const float* proto  = (const float*)d_in[1];
    const float* gumbel = (const float*)d_in[2];
    float* out = (float*)d_out;
    float* ws  = (float*)d_ws;

    ushort_t* Xh   = (ushort_t*)(out + OUT_PT);     // f16 x-hat in pt region
    ushort_t* Ph   = (ushort_t*)(ws + WS_PH);
    ushort_t* PTh  = (ushort_t*)(ws + WS_PTH);
    ushort_t* simh = (ushort_t*)(ws + WS_SIM);      // f16 sim, then Eh in-place

    norm_p_kernel<<<K / 4, 256, 0, stream>>>(proto, out, ws, Ph);
    {
        dim3 grid(K / 64, D / 64);
        ptcvt_kernel<<<grid, 256, 0, stream>>>(out, PTh);
    }
    xcvt_kernel<<<B / 4, 256, 0, stream>>>(input, Xh);
    {
        // simh = Xh · Ph^T   (A: [B][512], B: [K][512], C: [B][K] f16)
        dim3 grid(K / 256, B / 256);     // 4 x 64 = 256 blocks = 1/CU
        gemm256<256, 512, 512, K, 512, true><<<grid, 512, 0, stream>>>(Xh, Ph, simh);
    }
    softmax_rows<<<1024, 256, 0, stream>>>(gumbel, ws);
    {
        // pt = Eh · PTh^T   (A: [B][1024] f16, B: [512][1024], C: [B][512] fp32)
        dim3 grid(D / 128, B / 256);     // 4 x 64 = 256 blocks = 1/CU
        gemm256<128, 1024, 1024, D, 1024, false><<<grid, 512, 0, stream>>>(simh, PTh, out + OUT_PT);
    }
    finalize_kernel<<<1, 1024, 0, stream>>>(out, ws);
}

// Round 8
// 207.882 us; speedup vs baseline: 1.1126x; 1.1126x over previous
//
#include <hip/hip_runtime.h>
#include <math.h>

// Problem constants
#define B  16384
#define K  1024
#define D  512
#define EPS 1e-12f

// softmax in base-2: log2(e^{(s+g)/tau}) = SM_C1*s - 10*log2(-log2(u)) + SM_C2
//   tau = 0.1 ; SM_C1 = 10*log2(e) ; SM_C2 = -10*log2(ln 2)
#define SM_C1 14.426950408889634f
#define SM_C2 5.287663729448977f

typedef unsigned short ushort_t;

// raw gfx950 transcendentals: v_log_f32 = log2(x), v_exp_f32 = 2^x
#define LOG2F(x) __builtin_amdgcn_logf(x)
#define EXP2F(x) __builtin_amdgcn_exp2f(x)

// d_out layout (floats): [0, B*D) pt ; [B*D, B*D+K*D) p ; then sim_loss, div_loss
#define OUT_PT   0
#define OUT_P    (B*D)
#define OUT_SIM  (B*D + K*D)
#define OUT_DIV  (B*D + K*D + 1)

// ws layout (floats):
//  [1024,2048)      softmax per-block dot partials (1024)
//  [32768, +B*K/2)  simh f16 [B][1024]; after softmax same bytes hold Eh f16
//  then Ph   [1024][512] f16 (1 MB)
//  then PTh  [512][1024] f16 (1 MB)
//  then DIAGP[256], COLP[256][512]  (norm_p per-block partials, no atomics)
#define WS_RED   1024
#define WS_SIM   32768
#define WS_PH    (WS_SIM + (B*K)/2)
#define WS_PTH   (WS_PH + (K*D)/2)
#define WS_DIAGP (WS_PTH + (K*D)/2)
#define WS_COLP  (WS_DIAGP + 256)

// Xh f16 [16384][512] (16 MB) lives in d_out's pt region, consumed by gemm1
// before gemm2 overwrites pt.

typedef _Float16 half8 __attribute__((ext_vector_type(8)));
typedef float f32x4 __attribute__((ext_vector_type(4)));

__device__ __forceinline__ float wave_reduce_sum(float v) {
    #pragma unroll
    for (int off = 32; off >= 1; off >>= 1) v += __shfl_down(v, off);
    return v;
}
__device__ __forceinline__ float wave_reduce_max(float v) {
    #pragma unroll
    for (int off = 32; off >= 1; off >>= 1) v = fmaxf(v, __shfl_down(v, off));
    return v;
}

__device__ __forceinline__ ushort_t f2h(float f) {
    _Float16 h = (_Float16)f;
    return __builtin_bit_cast(ushort_t, h);
}
__device__ __forceinline__ float h2f(ushort_t u) {
    return (float)__builtin_bit_cast(_Float16, u);
}

__device__ __forceinline__ void async16(const void* g, void* l) {
    __builtin_amdgcn_global_load_lds(
        (const __attribute__((address_space(1))) unsigned int*)g,
        (__attribute__((address_space(3))) unsigned int*)l, 16, 0, 0);
}

// Normalize prototypes (one wave per row, 4 rows/block). Fused outputs:
//  - phat fp32 -> d_out (output 1)
//  - Ph f16 [1024][512]
//  - per-block colsum partial [512] -> ws[WS_COLP + blk*512]
//  - per-block diag partial -> ws[WS_DIAGP + blk]
__global__ __launch_bounds__(256) void norm_p_kernel(const float* __restrict__ proto,
                                                     float* __restrict__ out,
                                                     float* __restrict__ ws,
                                                     ushort_t* __restrict__ Ph) {
    __shared__ float cs[4][512];
    __shared__ float red[4];
    int tid = threadIdx.x, wid = tid >> 6, lane = tid & 63;
    int row = blockIdx.x * 4 + wid;
    const float4* pr = (const float4*)(proto + (size_t)row * D);
    float4 a = pr[lane * 2], b = pr[lane * 2 + 1];
    float ss = a.x*a.x + a.y*a.y + a.z*a.z + a.w*a.w
             + b.x*b.x + b.y*b.y + b.z*b.z + b.w*b.w;
    ss = wave_reduce_sum(ss);
    ss = __shfl(ss, 0);
    float inv = 1.0f / fmaxf(sqrtf(ss), EPS);
    float4 na = make_float4(a.x*inv, a.y*inv, a.z*inv, a.w*inv);
    float4 nb = make_float4(b.x*inv, b.y*inv, b.z*inv, b.w*inv);
    float4* po = (float4*)(out + OUT_P + (size_t)row * D);
    po[lane * 2]     = na;
    po[lane * 2 + 1] = nb;
    ushort4* ph = (ushort4*)(Ph + (size_t)row * D);
    ph[lane * 2]     = make_ushort4(f2h(na.x), f2h(na.y), f2h(na.z), f2h(na.w));
    ph[lane * 2 + 1] = make_ushort4(f2h(nb.x), f2h(nb.y), f2h(nb.z), f2h(nb.w));
    *(float4*)(&cs[wid][lane * 8])     = na;
    *(float4*)(&cs[wid][lane * 8 + 4]) = nb;
    if (lane == 0) red[wid] = ss * inv * inv;
    __syncthreads();
    float c0 = cs[0][tid] + cs[1][tid] + cs[2][tid] + cs[3][tid];
    float c1 = cs[0][tid + 256] + cs[1][tid + 256] + cs[2][tid + 256] + cs[3][tid + 256];
    ws[WS_COLP + (size_t)blockIdx.x * 512 + tid]       = c0;
    ws[WS_COLP + (size_t)blockIdx.x * 512 + tid + 256] = c1;
    if (tid == 0) ws[WS_DIAGP + blockIdx.x] = red[0] + red[1] + red[2] + red[3];
}

// PTh [512][1024] f16: transpose of phat
__global__ __launch_bounds__(256) void ptcvt_kernel(const float* __restrict__ out,
                                                    ushort_t* __restrict__ PT) {
    __shared__ float tile[64][65];
    int k0 = blockIdx.x * 64, d0 = blockIdx.y * 64;
    int tid = threadIdx.x;
    const float* phat = out + OUT_P;
    #pragma unroll
    for (int i = tid; i < 64 * 64; i += 256) {
        int kk = i >> 6, dd = i & 63;
        tile[dd][kk] = phat[(size_t)(k0 + kk) * D + d0 + dd];
    }
    __syncthreads();
    #pragma unroll
    for (int i = tid; i < 64 * 64; i += 256) {
        int dd = i >> 6, kk = i & 63;
        PT[(size_t)(d0 + dd) * K + k0 + kk] = f2h(tile[dd][kk]);
    }
}

// Fused x row-norm + f16 convert: Xh [16384][512] in out's pt region.
__global__ __launch_bounds__(256) void xcvt_kernel(const float* __restrict__ x,
                                                   ushort_t* __restrict__ Xh) {
    int wid = threadIdx.x >> 6, lane = threadIdx.x & 63;
    int row = blockIdx.x * 4 + wid;
    const float4* xr = (const float4*)(x + (size_t)row * D);
    float4 a = xr[lane * 2], b = xr[lane * 2 + 1];
    float ss = a.x*a.x + a.y*a.y + a.z*a.z + a.w*a.w
             + b.x*b.x + b.y*b.y + b.z*b.z + b.w*b.w;
    ss = wave_reduce_sum(ss);
    ss = __shfl(ss, 0);
    float inv = 1.0f / fmaxf(sqrtf(ss), EPS);
    ushort4 h0 = make_ushort4(f2h(a.x*inv), f2h(a.y*inv), f2h(a.z*inv), f2h(a.w*inv));
    ushort4 h1 = make_ushort4(f2h(b.x*inv), f2h(b.y*inv), f2h(b.z*inv), f2h(b.w*inv));
    ushort4* xo = (ushort4*)(Xh + (size_t)row * D);
    xo[lane * 2]     = h0;
    xo[lane * 2 + 1] = h1;
}

// f16 bt-GEMM, BK=64 via TWO independent 32-k panels (m97 recipe per panel):
// 128x128 block tile, 4 waves (2x2), 4x4 16x16x32-f16 MFMA tiles per wave per
// panel -> 32 MFMA per barrier pair. global_load_lds width-16 staging.
// F16C: write C as f16 (for simh), else fp32.
// T1 XCD-locality: launched 1-D over NBM*NBN blocks; sid is remapped so all
// NBN blocks sharing an A-panel (same bm) run on the SAME XCD (sid&7), making
// A re-reads L2-hits instead of per-XCD HBM re-fetches (round-7 counter
// evidence: FETCH 66.6 MB vs 17 MB ideal with the default round-robin).
template<int LDA, int LDB, int LDC, int KK, bool F16C, int NBN, int NBM>
__global__ __launch_bounds__(256) void gemm_bt2(const ushort_t* __restrict__ A,
                                                const ushort_t* __restrict__ Bm,
                                                void* __restrict__ Cv) {
    __shared__ __align__(16) ushort_t As[2 * 128 * 32];
    __shared__ __align__(16) ushort_t Bs[2 * 128 * 32];
    int tid = threadIdx.x;
    int wid = tid >> 6, lane = tid & 63;
    int quad = lane >> 4, l16 = lane & 15;
    int wm = (wid & 1) * 64, wn = (wid >> 1) * 64;

    // XCD-aware block swizzle: xcd = sid&7 owns bm in [xcd*NBM/8, (xcd+1)*NBM/8)
    int sid = blockIdx.x;
    int xcd = sid & 7, slot = sid >> 3;
    int bmb = xcd * (NBM / 8) + slot / NBN;
    int bnb = slot % NBN;
    int bn0 = bnb * 128, bm0 = bmb * 128;

    int ldrow = lane >> 2;           // 0..15
    int lcol  = (lane & 3) * 8;      // halves within a 32-half panel row

    f32x4 acc[4][4] = {};

    // wave-uniform LDS staging bases: panel p, row-group q
    ushort_t* AsD[2][2] = {
        { As + (wid * 16) * 32,        As + (64 + wid * 16) * 32 },
        { As + 4096 + (wid * 16) * 32, As + 4096 + (64 + wid * 16) * 32 } };
    ushort_t* BsD[2][2] = {
        { Bs + (wid * 16) * 32,        Bs + (64 + wid * 16) * 32 },
        { Bs + 4096 + (wid * 16) * 32, Bs + 4096 + (64 + wid * 16) * 32 } };

    const ushort_t* Ab = A + (size_t)(bm0 + wid * 16 + ldrow) * LDA + lcol;
    const ushort_t* Bb = Bm + (size_t)(bn0 + wid * 16 + ldrow) * LDB + lcol;

    for (int kc = 0; kc < KK; kc += 64) {
        async16(Ab + kc,                       AsD[0][0]);
        async16(Ab + kc + (size_t)64 * LDA,    AsD[0][1]);
        async16(Ab + kc + 32,                  AsD[1][0]);
        async16(Ab + kc + 32 + (size_t)64*LDA, AsD[1][1]);
        async16(Bb + kc,                       BsD[0][0]);
        async16(Bb + kc + (size_t)64 * LDB,    BsD[0][1]);
        async16(Bb + kc + 32,                  BsD[1][0]);
        async16(Bb + kc + 32 + (size_t)64*LDB, BsD[1][1]);
        __syncthreads();
        #pragma unroll
        for (int p = 0; p < 2; ++p) {
            half8 af[4], bg[4];
            #pragma unroll
            for (int i = 0; i < 4; ++i)
                af[i] = *(const half8*)(As + p * 4096 + (wm + 16 * i + l16) * 32 + quad * 8);
            #pragma unroll
            for (int j = 0; j < 4; ++j)
                bg[j] = *(const half8*)(Bs + p * 4096 + (wn + 16 * j + l16) * 32 + quad * 8);
            #pragma unroll
            for (int i = 0; i < 4; ++i)
                #pragma unroll
                for (int j = 0; j < 4; ++j)
                    acc[i][j] = __builtin_amdgcn_mfma_f32_16x16x32_f16(af[i], bg[j], acc[i][j], 0, 0, 0);
        }
        __syncthreads();
    }
    #pragma unroll
    for (int i = 0; i < 4; ++i) {
        #pragma unroll
        for (int j = 0; j < 4; ++j) {
            #pragma unroll
            for (int r = 0; r < 4; ++r) {
                int row = bm0 + wm + 16 * i + quad * 4 + r;
                int col = bn0 + wn + 16 * j + l16;
                if (F16C)
                    ((ushort_t*)Cv)[(size_t)row * LDC + col] = f2h(acc[i][j][r]);
                else
                    ((float*)Cv)[(size_t)row * LDC + col] = acc[i][j][r];
            }
        }
    }
}

// Row softmax with gumbel, base-2 domain (2x v_log + 1x v_exp per element).
// One WAVE per row, 4 rows/wave. Reads simh f16, writes Eh f16 in-place.
__global__ __launch_bounds__(256) void softmax_rows(const float* __restrict__ u,
                                                    float* __restrict__ ws) {
    ushort_t* simh = (ushort_t*)(ws + WS_SIM);
    int tid = threadIdx.x;
    int wid = tid >> 6, lane = tid & 63;
    int gw = blockIdx.x * 4 + wid;        // 0..4095
    float dotacc = 0.0f;

    for (int r = 0; r < 4; ++r) {
        int row = gw + 4096 * r;
        ushort4* srow = (ushort4*)(simh + (size_t)row * K);
        const float4* urow = (const float4*)(u + (size_t)row * K);
        float4 s[4], z[4];
        #pragma unroll
        for (int j = 0; j < 4; ++j) {
            ushort4 sh = srow[lane + 64 * j];
            float4 uu = urow[lane + 64 * j];
            s[j] = make_float4(h2f(sh.x), h2f(sh.y), h2f(sh.z), h2f(sh.w));
            z[j].x = SM_C1 * s[j].x - 10.0f * LOG2F(-LOG2F(uu.x)) + SM_C2;
            z[j].y = SM_C1 * s[j].y - 10.0f * LOG2F(-LOG2F(uu.y)) + SM_C2;
            z[j].z = SM_C1 * s[j].z - 10.0f * LOG2F(-LOG2F(uu.z)) + SM_C2;
            z[j].w = SM_C1 * s[j].w - 10.0f * LOG2F(-LOG2F(uu.w)) + SM_C2;
        }
        float m = z[0].x;
        #pragma unroll
        for (int j = 0; j < 4; ++j)
            m = fmaxf(m, fmaxf(fmaxf(z[j].x, z[j].y), fmaxf(z[j].z, z[j].w)));
        m = wave_reduce_max(m);
        m = __shfl(m, 0);

        float4 e[4];
        float l = 0.0f;
        #pragma unroll
        for (int j = 0; j < 4; ++j) {
            e[j].x = EXP2F(z[j].x - m);
            e[j].y = EXP2F(z[j].y - m);
            e[j].z = EXP2F(z[j].z - m);
            e[j].w = EXP2F(z[j].w - m);
            l += e[j].x + e[j].y + e[j].z + e[j].w;
        }
        l = wave_reduce_sum(l);
        l = __shfl(l, 0);
        float inv = 1.0f / l;

        #pragma unroll
        for (int j = 0; j < 4; ++j) {
            float ex = e[j].x * inv, ey = e[j].y * inv,
                  ez = e[j].z * inv, ew = e[j].w * inv;
            srow[lane + 64 * j] = make_ushort4(f2h(ex), f2h(ey), f2h(ez), f2h(ew));
            dotacc += ex * s[j].x + ey * s[j].y + ez * s[j].z + ew * s[j].w;
        }
    }

    dotacc = wave_reduce_sum(dotacc);
    __shared__ float red[4];
    if (lane == 0) red[wid] = dotacc;
    __syncthreads();
    if (tid == 0) ws[WS_RED + blockIdx.x] = red[0] + red[1] + red[2] + red[3];
}

// Final reduction, 1024 threads: softmax dot partials (1024), diag partials
// (256), colsum partials (256 x 512 -> ||colsum||^2).
__global__ __launch_bounds__(1024) void finalize_kernel(float* __restrict__ out,
                                                        const float* __restrict__ ws) {
    __shared__ float cred[1024];
    __shared__ float rd[16], rs[16], rg[16];
    int tid = threadIdx.x, wid = tid >> 6, lane = tid & 63;
    int col = tid & 511, h = tid >> 9;    // h=0: b2 0..127, h=1: b2 128..255
    float c = 0.0f;
    #pragma unroll 8
    for (int b2 = h * 128; b2 < h * 128 + 128; ++b2)
        c += ws[WS_COLP + (size_t)b2 * 512 + col];
    cred[tid] = c;
    float vdot = ws[WS_RED + tid];
    float diag = (tid < 256) ? ws[WS_DIAGP + tid] : 0.0f;
    __syncthreads();
    float vssq = 0.0f;
    if (tid < 512) {
        float cc = cred[tid] + cred[tid + 512];
        vssq = cc * cc;
    }
    vdot = wave_reduce_sum(vdot);
    vssq = wave_reduce_sum(vssq);
    diag = wave_reduce_sum(diag);
    if (lane == 0) { rd[wid] = vdot; rs[wid] = vssq; rg[wid] = diag; }
    __syncthreads();
    if (tid == 0) {
        float dot = 0.0f, ssq = 0.0f, dg = 0.0f;
        #pragma unroll
        for (int w = 0; w < 16; ++w) { dot += rd[w]; ssq += rs[w]; dg += rg[w]; }
        out[OUT_SIM] = 1.0f - dot * (1.0f / (float)B);
        out[OUT_DIV] = ssq - dg;
    }
}

extern "C" void kernel_launch(void* const* d_in, const int* in_sizes, int n_in,
                              void* d_out, int out_size, void* d_ws, size_t ws_size,
                              hipStream_t stream) {
    const float* input  = (const float*)d_in[0];
    const float* proto  = (const float*)d_in[1];
    const float* gumbel = (const float*)d_in[2];
    float* out = (float*)d_out;
    float* ws  = (float*)d_ws;

    ushort_t* Xh   = (ushort_t*)(out + OUT_PT);     // f16 x-hat in pt region
    ushort_t* Ph   = (ushort_t*)(ws + WS_PH);
    ushort_t* PTh  = (ushort_t*)(ws + WS_PTH);
    ushort_t* simh = (ushort_t*)(ws + WS_SIM);      // f16 sim, then Eh in-place

    norm_p_kernel<<<K / 4, 256, 0, stream>>>(proto, out, ws, Ph);
    {
        dim3 grid(K / 64, D / 64);
        ptcvt_kernel<<<grid, 256, 0, stream>>>(out, PTh);
    }
    xcvt_kernel<<<B / 4, 256, 0, stream>>>(input, Xh);
    {
        // simh = Xh · Ph^T   (A: [B][512], B: [K][512], C: [B][K] f16)
        // 1-D grid, XCD-swizzled inside: NBN=8 (K/128), NBM=128 (B/128)
        gemm_bt2<512, 512, K, 512, true, 8, 128>
            <<<(K / 128) * (B / 128), 256, 0, stream>>>(Xh, Ph, simh);
    }
    softmax_rows<<<1024, 256, 0, stream>>>(gumbel, ws);
    {
        // pt = Eh · PTh^T   (A: [B][1024] f16, B: [512][1024], C: [B][512] fp32)
        // NBN=4 (D/128), NBM=128 (B/128)
        gemm_bt2<1024, 1024, D, 1024, false, 4, 128>
            <<<(D / 128) * (B / 128), 256, 0, stream>>>(simh, PTh, out + OUT_PT);
    }
    finalize_kernel<<<1, 1024, 0, stream>>>(out, ws);
}

// Round 9
// 191.162 us; speedup vs baseline: 1.2099x; 1.0875x over previous
//
#include <hip/hip_runtime.h>
#include <math.h>

// Problem constants
#define B  16384
#define K  1024
#define D  512
#define EPS 1e-12f

// softmax in base-2: log2(e^{(s+g)/tau}) = SM_C1*s - 10*log2(-log2(u)) + SM_C2
//   tau = 0.1 ; SM_C1 = 10*log2(e) ; SM_C2 = -10*log2(ln 2)
#define SM_C1 14.426950408889634f
#define SM_C2 5.287663729448977f

typedef unsigned short ushort_t;

// raw gfx950 transcendentals: v_log_f32 = log2(x), v_exp_f32 = 2^x
#define LOG2F(x) __builtin_amdgcn_logf(x)
#define EXP2F(x) __builtin_amdgcn_exp2f(x)

// d_out layout (floats): [0, B*D) pt ; [B*D, B*D+K*D) p ; then sim_loss, div_loss
#define OUT_PT   0
#define OUT_P    (B*D)
#define OUT_SIM  (B*D + K*D)
#define OUT_DIV  (B*D + K*D + 1)

// ws layout (floats):
//  [1024,2048)      softmax per-block dot partials (1024)
//  [32768, +B*K/2)  simh f16 [B][1024]; after softmax same bytes hold Eh f16
//  then Ph   [1024][512] f16 (1 MB)
//  then PTh  [512][1024] f16 (1 MB)
//  then DIAGP[256], COLP[256][512]  (norm_p per-block partials, no atomics)
#define WS_RED   1024
#define WS_SIM   32768
#define WS_PH    (WS_SIM + (B*K)/2)
#define WS_PTH   (WS_PH + (K*D)/2)
#define WS_DIAGP (WS_PTH + (K*D)/2)
#define WS_COLP  (WS_DIAGP + 256)

// Xh f16 [16384][512] (16 MB) lives in d_out's pt region, consumed by gemm1
// before gemm2 overwrites pt.

typedef _Float16 half8 __attribute__((ext_vector_type(8)));
typedef float f32x4 __attribute__((ext_vector_type(4)));

__device__ __forceinline__ float wave_reduce_sum(float v) {
    #pragma unroll
    for (int off = 32; off >= 1; off >>= 1) v += __shfl_down(v, off);
    return v;
}
__device__ __forceinline__ float wave_reduce_max(float v) {
    #pragma unroll
    for (int off = 32; off >= 1; off >>= 1) v = fmaxf(v, __shfl_down(v, off));
    return v;
}

__device__ __forceinline__ ushort_t f2h(float f) {
    _Float16 h = (_Float16)f;
    return __builtin_bit_cast(ushort_t, h);
}
__device__ __forceinline__ float h2f(ushort_t u) {
    return (float)__builtin_bit_cast(_Float16, u);
}

__device__ __forceinline__ void async16(const void* g, void* l) {
    __builtin_amdgcn_global_load_lds(
        (const __attribute__((address_space(1))) unsigned int*)g,
        (__attribute__((address_space(3))) unsigned int*)l, 16, 0, 0);
}

// ---------------------------------------------------------------------------
// prep: norm_p (blocks 0..255) || xcvt (blocks 256..4351) — independent work
// merged into one launch to cut graph-launch gaps.
// ---------------------------------------------------------------------------
__global__ __launch_bounds__(256) void prep_kernel(const float* __restrict__ proto,
                                                   const float* __restrict__ x,
                                                   float* __restrict__ out,
                                                   float* __restrict__ ws,
                                                   ushort_t* __restrict__ Ph,
                                                   ushort_t* __restrict__ Xh) {
    __shared__ float cs[4][512];
    __shared__ float red[4];
    int tid = threadIdx.x, wid = tid >> 6, lane = tid & 63;

    if (blockIdx.x < 256) {
        // ---- norm_p: normalize prototypes, 4 rows/block ----
        int row = blockIdx.x * 4 + wid;
        const float4* pr = (const float4*)(proto + (size_t)row * D);
        float4 a = pr[lane * 2], b = pr[lane * 2 + 1];
        float ss = a.x*a.x + a.y*a.y + a.z*a.z + a.w*a.w
                 + b.x*b.x + b.y*b.y + b.z*b.z + b.w*b.w;
        ss = wave_reduce_sum(ss);
        ss = __shfl(ss, 0);
        float inv = 1.0f / fmaxf(sqrtf(ss), EPS);
        float4 na = make_float4(a.x*inv, a.y*inv, a.z*inv, a.w*inv);
        float4 nb = make_float4(b.x*inv, b.y*inv, b.z*inv, b.w*inv);
        float4* po = (float4*)(out + OUT_P + (size_t)row * D);
        po[lane * 2]     = na;
        po[lane * 2 + 1] = nb;
        ushort4* ph = (ushort4*)(Ph + (size_t)row * D);
        ph[lane * 2]     = make_ushort4(f2h(na.x), f2h(na.y), f2h(na.z), f2h(na.w));
        ph[lane * 2 + 1] = make_ushort4(f2h(nb.x), f2h(nb.y), f2h(nb.z), f2h(nb.w));
        *(float4*)(&cs[wid][lane * 8])     = na;
        *(float4*)(&cs[wid][lane * 8 + 4]) = nb;
        if (lane == 0) red[wid] = ss * inv * inv;
        __syncthreads();
        float c0 = cs[0][tid] + cs[1][tid] + cs[2][tid] + cs[3][tid];
        float c1 = cs[0][tid + 256] + cs[1][tid + 256] + cs[2][tid + 256] + cs[3][tid + 256];
        ws[WS_COLP + (size_t)blockIdx.x * 512 + tid]       = c0;
        ws[WS_COLP + (size_t)blockIdx.x * 512 + tid + 256] = c1;
        if (tid == 0) ws[WS_DIAGP + blockIdx.x] = red[0] + red[1] + red[2] + red[3];
    } else {
        // ---- xcvt: x row-norm + f16 convert, 4 rows/block ----
        int row = (blockIdx.x - 256) * 4 + wid;
        const float4* xr = (const float4*)(x + (size_t)row * D);
        float4 a = xr[lane * 2], b = xr[lane * 2 + 1];
        float ss = a.x*a.x + a.y*a.y + a.z*a.z + a.w*a.w
                 + b.x*b.x + b.y*b.y + b.z*b.z + b.w*b.w;
        ss = wave_reduce_sum(ss);
        ss = __shfl(ss, 0);
        float inv = 1.0f / fmaxf(sqrtf(ss), EPS);
        ushort4 h0 = make_ushort4(f2h(a.x*inv), f2h(a.y*inv), f2h(a.z*inv), f2h(a.w*inv));
        ushort4 h1 = make_ushort4(f2h(b.x*inv), f2h(b.y*inv), f2h(b.z*inv), f2h(b.w*inv));
        ushort4* xo = (ushort4*)(Xh + (size_t)row * D);
        xo[lane * 2]     = h0;
        xo[lane * 2 + 1] = h1;
    }
}

// ---------------------------------------------------------------------------
// f16 bt-GEMM (m97 recipe) + T1 XCD swizzle + piggyback blocks.
// Blocks [0, NBM*NBN): GEMM with XCD-locality remap (all NBN same-A blocks on
// one XCD -> A re-reads are L2 hits; round-8: -8 µs, FETCH theory confirmed).
// Blocks >= NBM*NBN: EXTRA work riding the same launch (no intra-launch deps):
//   EXTRA==1 (gemm1): ptcvt — PTh[d][k] transpose of phat (input: prior launch)
//   EXTRA==2 (gemm2): finalize — loss reduction (inputs: prior launches)
// Shared memory is a union arena (gemm 16 KB | ptcvt 16.6 KB | finalize tiny).
// ---------------------------------------------------------------------------
template<int LDA, int LDB, int LDC, int KK, bool F16C, int NBN, int NBM, int EXTRA>
__global__ __launch_bounds__(256) void gemm_bt2(const ushort_t* __restrict__ A,
                                                const ushort_t* __restrict__ Bm,
                                                void* __restrict__ Cv,
                                                const float* __restrict__ phat,
                                                ushort_t* __restrict__ PT,
                                                float* __restrict__ out,
                                                float* __restrict__ ws) {
    __shared__ __align__(16) char smem[64 * 65 * 4];   // 16.6 KB arena
    int tid = threadIdx.x;
    int wid = tid >> 6, lane = tid & 63;

    if (blockIdx.x >= NBM * NBN) {
        if (EXTRA == 1) {
            // ---- ptcvt: PTh [512][1024] = transpose of phat, 64x64 tiles ----
            int pid = blockIdx.x - NBM * NBN;          // 0..127
            int k0 = (pid & 15) * 64, d0 = (pid >> 4) * 64;
            float (*tile)[65] = (float(*)[65])smem;
            #pragma unroll
            for (int i = tid; i < 64 * 64; i += 256) {
                int kk = i >> 6, dd = i & 63;
                tile[dd][kk] = phat[(size_t)(k0 + kk) * D + d0 + dd];
            }
            __syncthreads();
            #pragma unroll
            for (int i = tid; i < 64 * 64; i += 256) {
                int dd = i >> 6, kk = i & 63;
                PT[(size_t)(d0 + dd) * K + k0 + kk] = f2h(tile[dd][kk]);
            }
        } else if (EXTRA == 2) {
            // ---- finalize (256 threads): runs concurrent with gemm2 ----
            float* rd = (float*)smem;                  // [4]x3
            float* rs = rd + 4;
            float* rg = rs + 4;
            float vdot = 0.0f;
            #pragma unroll
            for (int i = 0; i < 4; ++i) vdot += ws[WS_RED + tid + 256 * i];
            float diag = ws[WS_DIAGP + tid];
            float c0 = 0.0f, c1 = 0.0f;
            #pragma unroll 8
            for (int b2 = 0; b2 < 256; ++b2) {
                c0 += ws[WS_COLP + (size_t)b2 * 512 + tid];
                c1 += ws[WS_COLP + (size_t)b2 * 512 + tid + 256];
            }
            float vssq = c0 * c0 + c1 * c1;
            vdot = wave_reduce_sum(vdot);
            vssq = wave_reduce_sum(vssq);
            diag = wave_reduce_sum(diag);
            if (lane == 0) { rd[wid] = vdot; rs[wid] = vssq; rg[wid] = diag; }
            __syncthreads();
            if (tid == 0) {
                float dot = rd[0] + rd[1] + rd[2] + rd[3];
                float ssq = rs[0] + rs[1] + rs[2] + rs[3];
                float dg  = rg[0] + rg[1] + rg[2] + rg[3];
                out[OUT_SIM] = 1.0f - dot * (1.0f / (float)B);
                out[OUT_DIV] = ssq - dg;
            }
        }
        return;
    }

    // ---- GEMM path ----
    ushort_t* As = (ushort_t*)smem;                    // 2*128*32 halves = 8 KB
    ushort_t* Bs = (ushort_t*)(smem + 8192);

    int quad = lane >> 4, l16 = lane & 15;
    int wm = (wid & 1) * 64, wn = (wid >> 1) * 64;

    // XCD-aware block swizzle: xcd = sid&7 owns bm in [xcd*NBM/8, (xcd+1)*NBM/8)
    int sid = blockIdx.x;
    int xcd = sid & 7, slot = sid >> 3;
    int bmb = xcd * (NBM / 8) + slot / NBN;
    int bnb = slot % NBN;
    int bn0 = bnb * 128, bm0 = bmb * 128;

    int ldrow = lane >> 2;           // 0..15
    int lcol  = (lane & 3) * 8;      // halves within a 32-half panel row

    f32x4 acc[4][4] = {};

    // wave-uniform LDS staging bases: panel p, row-group q
    ushort_t* AsD[2][2] = {
        { As + (wid * 16) * 32,        As + (64 + wid * 16) * 32 },
        { As + 4096 + (wid * 16) * 32, As + 4096 + (64 + wid * 16) * 32 } };
    ushort_t* BsD[2][2] = {
        { Bs + (wid * 16) * 32,        Bs + (64 + wid * 16) * 32 },
        { Bs + 4096 + (wid * 16) * 32, Bs + 4096 + (64 + wid * 16) * 32 } };

    const ushort_t* Ab = A + (size_t)(bm0 + wid * 16 + ldrow) * LDA + lcol;
    const ushort_t* Bb = Bm + (size_t)(bn0 + wid * 16 + ldrow) * LDB + lcol;

    for (int kc = 0; kc < KK; kc += 64) {
        async16(Ab + kc,                       AsD[0][0]);
        async16(Ab + kc + (size_t)64 * LDA,    AsD[0][1]);
        async16(Ab + kc + 32,                  AsD[1][0]);
        async16(Ab + kc + 32 + (size_t)64*LDA, AsD[1][1]);
        async16(Bb + kc,                       BsD[0][0]);
        async16(Bb + kc + (size_t)64 * LDB,    BsD[0][1]);
        async16(Bb + kc + 32,                  BsD[1][0]);
        async16(Bb + kc + 32 + (size_t)64*LDB, BsD[1][1]);
        __syncthreads();
        #pragma unroll
        for (int p = 0; p < 2; ++p) {
            half8 af[4], bg[4];
            #pragma unroll
            for (int i = 0; i < 4; ++i)
                af[i] = *(const half8*)(As + p * 4096 + (wm + 16 * i + l16) * 32 + quad * 8);
            #pragma unroll
            for (int j = 0; j < 4; ++j)
                bg[j] = *(const half8*)(Bs + p * 4096 + (wn + 16 * j + l16) * 32 + quad * 8);
            #pragma unroll
            for (int i = 0; i < 4; ++i)
                #pragma unroll
                for (int j = 0; j < 4; ++j)
                    acc[i][j] = __builtin_amdgcn_mfma_f32_16x16x32_f16(af[i], bg[j], acc[i][j], 0, 0, 0);
        }
        __syncthreads();
    }
    #pragma unroll
    for (int i = 0; i < 4; ++i) {
        #pragma unroll
        for (int j = 0; j < 4; ++j) {
            #pragma unroll
            for (int r = 0; r < 4; ++r) {
                int row = bm0 + wm + 16 * i + quad * 4 + r;
                int col = bn0 + wn + 16 * j + l16;
                if (F16C)
                    ((ushort_t*)Cv)[(size_t)row * LDC + col] = f2h(acc[i][j][r]);
                else
                    ((float*)Cv)[(size_t)row * LDC + col] = acc[i][j][r];
            }
        }
    }
}

// Row softmax with gumbel, base-2 domain (2x v_log + 1x v_exp per element).
// One WAVE per row, 4 rows/wave. Reads simh f16, writes Eh f16 in-place.
__global__ __launch_bounds__(256) void softmax_rows(const float* __restrict__ u,
                                                    float* __restrict__ ws) {
    ushort_t* simh = (ushort_t*)(ws + WS_SIM);
    int tid = threadIdx.x;
    int wid = tid >> 6, lane = tid & 63;
    int gw = blockIdx.x * 4 + wid;        // 0..4095
    float dotacc = 0.0f;

    for (int r = 0; r < 4; ++r) {
        int row = gw + 4096 * r;
        ushort4* srow = (ushort4*)(simh + (size_t)row * K);
        const float4* urow = (const float4*)(u + (size_t)row * K);
        float4 s[4], z[4];
        #pragma unroll
        for (int j = 0; j < 4; ++j) {
            ushort4 sh = srow[lane + 64 * j];
            float4 uu = urow[lane + 64 * j];
            s[j] = make_float4(h2f(sh.x), h2f(sh.y), h2f(sh.z), h2f(sh.w));
            z[j].x = SM_C1 * s[j].x - 10.0f * LOG2F(-LOG2F(uu.x)) + SM_C2;
            z[j].y = SM_C1 * s[j].y - 10.0f * LOG2F(-LOG2F(uu.y)) + SM_C2;
            z[j].z = SM_C1 * s[j].z - 10.0f * LOG2F(-LOG2F(uu.z)) + SM_C2;
            z[j].w = SM_C1 * s[j].w - 10.0f * LOG2F(-LOG2F(uu.w)) + SM_C2;
        }
        float m = z[0].x;
        #pragma unroll
        for (int j = 0; j < 4; ++j)
            m = fmaxf(m, fmaxf(fmaxf(z[j].x, z[j].y), fmaxf(z[j].z, z[j].w)));
        m = wave_reduce_max(m);
        m = __shfl(m, 0);

        float4 e[4];
        float l = 0.0f;
        #pragma unroll
        for (int j = 0; j < 4; ++j) {
            e[j].x = EXP2F(z[j].x - m);
            e[j].y = EXP2F(z[j].y - m);
            e[j].z = EXP2F(z[j].z - m);
            e[j].w = EXP2F(z[j].w - m);
            l += e[j].x + e[j].y + e[j].z + e[j].w;
        }
        l = wave_reduce_sum(l);
        l = __shfl(l, 0);
        float inv = 1.0f / l;

        #pragma unroll
        for (int j = 0; j < 4; ++j) {
            float ex = e[j].x * inv, ey = e[j].y * inv,
                  ez = e[j].z * inv, ew = e[j].w * inv;
            srow[lane + 64 * j] = make_ushort4(f2h(ex), f2h(ey), f2h(ez), f2h(ew));
            dotacc += ex * s[j].x + ey * s[j].y + ez * s[j].z + ew * s[j].w;
        }
    }

    dotacc = wave_reduce_sum(dotacc);
    __shared__ float red[4];
    if (lane == 0) red[wid] = dotacc;
    __syncthreads();
    if (tid == 0) ws[WS_RED + blockIdx.x] = red[0] + red[1] + red[2] + red[3];
}

extern "C" void kernel_launch(void* const* d_in, const int* in_sizes, int n_in,
                              void* d_out, int out_size, void* d_ws, size_t ws_size,
                              hipStream_t stream) {
    const float* input  = (const float*)d_in[0];
    const float* proto  = (const float*)d_in[1];
    const float* gumbel = (const float*)d_in[2];
    float* out = (float*)d_out;
    float* ws  = (float*)d_ws;

    ushort_t* Xh   = (ushort_t*)(out + OUT_PT);     // f16 x-hat in pt region
    ushort_t* Ph   = (ushort_t*)(ws + WS_PH);
    ushort_t* PTh  = (ushort_t*)(ws + WS_PTH);
    ushort_t* simh = (ushort_t*)(ws + WS_SIM);      // f16 sim, then Eh in-place

    // 1) norm_p || xcvt (independent)
    prep_kernel<<<256 + B / 4, 256, 0, stream>>>(proto, input, out, ws, Ph, Xh);

    // 2) simh = Xh · Ph^T  (+ piggyback ptcvt blocks: PTh = phat^T)
    gemm_bt2<512, 512, K, 512, true, 8, 128, 1>
        <<<(K / 128) * (B / 128) + 128, 256, 0, stream>>>(
            Xh, Ph, simh, out + OUT_P, PTh, out, ws);

    // 3) row softmax with gumbel (in-place simh -> Eh)
    softmax_rows<<<1024, 256, 0, stream>>>(gumbel, ws);

    // 4) pt = Eh · PTh^T  (+ piggyback finalize block: losses from partials)
    gemm_bt2<1024, 1024, D, 1024, false, 4, 128, 2>
        <<<(D / 128) * (B / 128) + 1, 256, 0, stream>>>(
            simh, PTh, out + OUT_PT, out + OUT_P, PTh, out, ws);
}